// Round 1
// baseline (179.203 us; speedup 1.0000x reference)
//
#include <hip/hip_runtime.h>

// Problem constants (match reference: B=16, S=4096, D=128)
#define BB   16
#define SS   4096
#define DD   128
#define NCH  256            // chunks per batch
#define TT   (SS / NCH)     // 16 steps per chunk
#define GPB  4              // 32-lane groups (=chunks) per block
#define NTHR 128

#define LN_EPS  1e-5f
#define REC_EPS 1e-8f

__device__ __forceinline__ float fast_rcp(float x) { return __builtin_amdgcn_rcpf(x); }
__device__ __forceinline__ float sigm(float x) { return fast_rcp(1.0f + __expf(-x)); }

// Butterfly-reduce two floats across a 32-lane group (xor masks <=16 stay
// within each 32-lane half of the 64-lane wave). All lanes get the sum.
__device__ __forceinline__ void red2(float& a, float& b) {
#pragma unroll
    for (int m = 16; m >= 1; m >>= 1) {
        a += __shfl_xor(a, m, 64);
        b += __shfl_xor(b, m, 64);
    }
}

// ---------------------------------------------------------------------------
// Pass 1: per-chunk transfer functions.
//   bst recurrence per d: state' = decay*state + (exp(c)*v + ctx_add)
//     chunk transfer: (P[d], Q[d])  via P*=decay, Q = decay*Q + term
//   a recurrence (scalar): a' = m_t*a + e_t,   chunk transfer (Pa, Qa)
//   also stores per-step m_t, e_t for pass 3.
// ---------------------------------------------------------------------------
__global__ __launch_bounds__(NTHR) void pass1_kernel(
    const float* __restrict__ C, const float* __restrict__ V, const float* __restrict__ W,
    const float* __restrict__ enc, const float* __restrict__ tmod, const float* __restrict__ cmod,
    float* __restrict__ Pbuf, float* __restrict__ Qbuf,
    float* __restrict__ PaBuf, float* __restrict__ QaBuf,
    float* __restrict__ mbuf, float* __restrict__ ebuf)
{
    const int grp  = threadIdx.x >> 5;
    const int lane = threadIdx.x & 31;
    const int gc   = blockIdx.x * GPB + grp;       // global chunk id = b*NCH + ch
    const int b    = gc >> 8;                      // / NCH (256)
    const int ch   = gc & (NCH - 1);
    const int d4   = lane << 2;

    const float4 tm = *(const float4*)(tmod + d4);
    const float4 cm = *(const float4*)(cmod + d4);
    const float4 ec = *(const float4*)(enc + b * DD + d4);
    float4 ctx;
    ctx.x = sigm(ec.x * cm.x) * ec.x;
    ctx.y = sigm(ec.y * cm.y) * ec.y;
    ctx.z = sigm(ec.z * cm.z) * ec.z;
    ctx.w = sigm(ec.w * cm.w) * ec.w;

    float4 P = make_float4(1.f, 1.f, 1.f, 1.f);
    float4 Q = make_float4(0.f, 0.f, 0.f, 0.f);
    float pa = 1.f, qa = 0.f;

    const int t0 = ch * TT;
    const size_t base = ((size_t)b * SS + t0) * DD + d4;
    const float4* Cp = (const float4*)(C + base);
    const float4* Vp = (const float4*)(V + base);
    const float4* Wp = (const float4*)(W + base);

#pragma unroll 4
    for (int t = 0; t < TT; ++t) {
        const float4 c4 = Cp[t * (DD / 4)];
        const float4 v4 = Vp[t * (DD / 4)];
        const float4 w4 = Wp[t * (DD / 4)];
        float4 dec, e4;
        dec.x = sigm(w4.x * tm.x); dec.y = sigm(w4.y * tm.y);
        dec.z = sigm(w4.z * tm.z); dec.w = sigm(w4.w * tm.w);
        e4.x = __expf(c4.x); e4.y = __expf(c4.y);
        e4.z = __expf(c4.z); e4.w = __expf(c4.w);

        Q.x = dec.x * Q.x + (e4.x * v4.x + ctx.x);
        Q.y = dec.y * Q.y + (e4.y * v4.y + ctx.y);
        Q.z = dec.z * Q.z + (e4.z * v4.z + ctx.z);
        Q.w = dec.w * Q.w + (e4.w * v4.w + ctx.w);
        P.x *= dec.x; P.y *= dec.y; P.z *= dec.z; P.w *= dec.w;

        float sd = (dec.x + dec.y) + (dec.z + dec.w);
        float se = (e4.x + e4.y) + (e4.z + e4.w);
        red2(sd, se);
        const float mt = sd * (1.0f / DD);
        pa *= mt;
        qa = mt * qa + se;
        if (lane == 0) {
            mbuf[(size_t)b * SS + t0 + t] = mt;
            ebuf[(size_t)b * SS + t0 + t] = se;
        }
    }

    *(float4*)(Pbuf + (size_t)gc * DD + d4) = P;
    *(float4*)(Qbuf + (size_t)gc * DD + d4) = Q;
    if (lane == 0) { PaBuf[gc] = pa; QaBuf[gc] = qa; }
}

// ---------------------------------------------------------------------------
// Pass 2: scan chunk transfer functions -> chunk-entry states.
//   Phase A: Kogge-Stone inclusive scan of (Pa,Qa) over NCH chunks; with
//            a_init = 0 the entry state of chunk ch is Q_incl[ch-1].
//   Phase B: sequential per-(b,d) scan of (P,Q) -> bst0 (entry bst state).
// ---------------------------------------------------------------------------
__global__ __launch_bounds__(NCH) void pass2_kernel(
    const float* __restrict__ Pbuf, const float* __restrict__ Qbuf,
    const float* __restrict__ PaBuf, const float* __restrict__ QaBuf,
    float* __restrict__ bst0, float* __restrict__ a0)
{
    const int b = blockIdx.x;
    const int tid = threadIdx.x;
    __shared__ float sP[NCH], sQ[NCH];

    float p = PaBuf[b * NCH + tid];
    float q = QaBuf[b * NCH + tid];
#pragma unroll
    for (int off = 1; off < NCH; off <<= 1) {
        sP[tid] = p; sQ[tid] = q;
        __syncthreads();
        if (tid >= off) {
            const float pp = sP[tid - off], qq = sQ[tid - off];
            q = p * qq + q;   // apply earlier transfer first, then ours
            p = p * pp;
        }
        __syncthreads();
    }
    sQ[tid] = q;
    __syncthreads();
    a0[b * NCH + tid] = (tid == 0) ? 0.f : sQ[tid - 1];

    if (tid < DD) {
        float s = 0.f;
#pragma unroll 8
        for (int ch = 0; ch < NCH; ++ch) {
            const size_t idx = ((size_t)b * NCH + ch) * DD + tid;
            bst0[idx] = s;
            s = Pbuf[idx] * s + Qbuf[idx];
        }
    }
}

// ---------------------------------------------------------------------------
// Pass 3: replay each chunk from its entry state; fuse LayerNorm; write out.
// ---------------------------------------------------------------------------
__global__ __launch_bounds__(NTHR) void pass3_kernel(
    const float* __restrict__ C, const float* __restrict__ V, const float* __restrict__ W,
    const float* __restrict__ enc, const float* __restrict__ tmod, const float* __restrict__ cmod,
    const float* __restrict__ lnw, const float* __restrict__ lnb,
    const float* __restrict__ bst0, const float* __restrict__ a0,
    const float* __restrict__ mbuf, const float* __restrict__ ebuf,
    float* __restrict__ out)
{
    const int grp  = threadIdx.x >> 5;
    const int lane = threadIdx.x & 31;
    const int gc   = blockIdx.x * GPB + grp;
    const int b    = gc >> 8;
    const int ch   = gc & (NCH - 1);
    const int d4   = lane << 2;

    const float4 tm = *(const float4*)(tmod + d4);
    const float4 cm = *(const float4*)(cmod + d4);
    const float4 ec = *(const float4*)(enc + b * DD + d4);
    float4 ctx;
    ctx.x = sigm(ec.x * cm.x) * ec.x;
    ctx.y = sigm(ec.y * cm.y) * ec.y;
    ctx.z = sigm(ec.z * cm.z) * ec.z;
    ctx.w = sigm(ec.w * cm.w) * ec.w;
    const float4 gw = *(const float4*)(lnw + d4);
    const float4 gb = *(const float4*)(lnb + d4);

    float4 bst = *(const float4*)(bst0 + (size_t)gc * DD + d4);
    float a = a0[gc];

    const int t0 = ch * TT;
    const size_t base = ((size_t)b * SS + t0) * DD + d4;
    const float4* Cp = (const float4*)(C + base);
    const float4* Vp = (const float4*)(V + base);
    const float4* Wp = (const float4*)(W + base);
    float4* Op = (float4*)(out + base);
    const float* mp = mbuf + (size_t)b * SS + t0;
    const float* ep = ebuf + (size_t)b * SS + t0;

#pragma unroll 2
    for (int t = 0; t < TT; ++t) {
        const float4 c4 = Cp[t * (DD / 4)];
        const float4 v4 = Vp[t * (DD / 4)];
        const float4 w4 = Wp[t * (DD / 4)];
        const float mt = mp[t];
        const float et = ep[t];

        float4 dec, e4;
        dec.x = sigm(w4.x * tm.x); dec.y = sigm(w4.y * tm.y);
        dec.z = sigm(w4.z * tm.z); dec.w = sigm(w4.w * tm.w);
        e4.x = __expf(c4.x); e4.y = __expf(c4.y);
        e4.z = __expf(c4.z); e4.w = __expf(c4.w);

        a = mt * a + et;
        bst.x = dec.x * bst.x + (e4.x * v4.x + ctx.x);
        bst.y = dec.y * bst.y + (e4.y * v4.y + ctx.y);
        bst.z = dec.z * bst.z + (e4.z * v4.z + ctx.z);
        bst.w = dec.w * bst.w + (e4.w * v4.w + ctx.w);

        const float inva = fast_rcp(a + REC_EPS);
        float4 o;
        o.x = bst.x * inva; o.y = bst.y * inva;
        o.z = bst.z * inva; o.w = bst.w * inva;

        float s1 = (o.x + o.y) + (o.z + o.w);
        float s2 = (o.x * o.x + o.y * o.y) + (o.z * o.z + o.w * o.w);
        red2(s1, s2);
        const float mu  = s1 * (1.0f / DD);
        const float var = s2 * (1.0f / DD) - mu * mu;
        const float rs  = rsqrtf(var + LN_EPS);

        float4 r;
        r.x = (o.x - mu) * rs * gw.x + gb.x;
        r.y = (o.y - mu) * rs * gw.y + gb.y;
        r.z = (o.z - mu) * rs * gw.z + gb.z;
        r.w = (o.w - mu) * rs * gw.w + gb.w;
        Op[t * (DD / 4)] = r;
    }
}

extern "C" void kernel_launch(void* const* d_in, const int* in_sizes, int n_in,
                              void* d_out, int out_size, void* d_ws, size_t ws_size,
                              hipStream_t stream)
{
    const float* C    = (const float*)d_in[0];
    const float* V    = (const float*)d_in[1];
    const float* W    = (const float*)d_in[2];
    const float* enc  = (const float*)d_in[3];
    const float* tmod = (const float*)d_in[4];
    const float* cmod = (const float*)d_in[5];
    const float* lnw  = (const float*)d_in[6];
    const float* lnb  = (const float*)d_in[7];
    float* out = (float*)d_out;

    // Workspace layout (floats): ~6.6 MB total
    float* ws    = (float*)d_ws;
    float* Pbuf  = ws;                          // BB*NCH*DD
    float* Qbuf  = Pbuf  + (size_t)BB * NCH * DD;
    float* bst0  = Qbuf  + (size_t)BB * NCH * DD;
    float* mbuf  = bst0  + (size_t)BB * NCH * DD;   // BB*SS
    float* ebuf  = mbuf  + (size_t)BB * SS;
    float* PaBuf = ebuf  + (size_t)BB * SS;         // BB*NCH
    float* QaBuf = PaBuf + (size_t)BB * NCH;
    float* a0Buf = QaBuf + (size_t)BB * NCH;

    const int nblk = BB * NCH / GPB;   // 1024
    pass1_kernel<<<nblk, NTHR, 0, stream>>>(C, V, W, enc, tmod, cmod,
                                            Pbuf, Qbuf, PaBuf, QaBuf, mbuf, ebuf);
    pass2_kernel<<<BB, NCH, 0, stream>>>(Pbuf, Qbuf, PaBuf, QaBuf, bst0, a0Buf);
    pass3_kernel<<<nblk, NTHR, 0, stream>>>(C, V, W, enc, tmod, cmod, lnw, lnb,
                                            bst0, a0Buf, mbuf, ebuf, out);
}

// Round 2
// 162.725 us; speedup vs baseline: 1.1013x; 1.1013x over previous
//
#include <hip/hip_runtime.h>

// Problem constants (match reference: B=16, S=4096, D=128)
#define BB   16
#define SS   4096
#define DD   128
#define NCH  256            // chunks per batch
#define TT   (SS / NCH)     // 16 steps per chunk
#define GPB  4              // 32-lane groups (=chunks) per block
#define NTHR 128

// pass2 two-level scan geometry
#define DT   16             // d's per pass2 block
#define SUBS 16             // sub-ranges per (b,d)
#define CPS  (NCH / SUBS)   // 16 chunks per sub-range

#define LN_EPS  1e-5f
#define REC_EPS 1e-8f

__device__ __forceinline__ float fast_rcp(float x) { return __builtin_amdgcn_rcpf(x); }
__device__ __forceinline__ float sigm(float x) { return fast_rcp(1.0f + __expf(-x)); }

// pack (decay, e) as bf16 pair: lo16 = decay, hi16 = e (round-half-up)
__device__ __forceinline__ unsigned pack_de(float d, float e) {
    unsigned ud = (__float_as_uint(d) + 0x8000u) >> 16;
    unsigned ue = (__float_as_uint(e) + 0x8000u) & 0xFFFF0000u;
    return ue | ud;
}
__device__ __forceinline__ float de_lo(unsigned u) { return __uint_as_float(u << 16); }
__device__ __forceinline__ float de_hi(unsigned u) { return __uint_as_float(u & 0xFFFF0000u); }

// Butterfly-reduce two floats across a 32-lane group (xor masks <=16 stay
// within each 32-lane half of the 64-lane wave). All lanes get the sum.
__device__ __forceinline__ void red2(float& a, float& b) {
#pragma unroll
    for (int m = 16; m >= 1; m >>= 1) {
        a += __shfl_xor(a, m, 64);
        b += __shfl_xor(b, m, 64);
    }
}

// ---------------------------------------------------------------------------
// Pass 1: per-chunk transfer functions + bf16 (decay, exp(c)) side-band.
// ---------------------------------------------------------------------------
__global__ __launch_bounds__(NTHR) void pass1_kernel(
    const float* __restrict__ C, const float* __restrict__ V, const float* __restrict__ W,
    const float* __restrict__ enc, const float* __restrict__ tmod, const float* __restrict__ cmod,
    unsigned* __restrict__ DE,
    float* __restrict__ Pbuf, float* __restrict__ Qbuf,
    float* __restrict__ PaBuf, float* __restrict__ QaBuf,
    float* __restrict__ mbuf, float* __restrict__ ebuf)
{
    const int grp  = threadIdx.x >> 5;
    const int lane = threadIdx.x & 31;
    const int gc   = blockIdx.x * GPB + grp;       // global chunk id = b*NCH + ch
    const int b    = gc >> 8;                      // / NCH (256)
    const int ch   = gc & (NCH - 1);
    const int d4   = lane << 2;

    const float4 tm = *(const float4*)(tmod + d4);
    const float4 cm = *(const float4*)(cmod + d4);
    const float4 ec = *(const float4*)(enc + b * DD + d4);
    float4 ctx;
    ctx.x = sigm(ec.x * cm.x) * ec.x;
    ctx.y = sigm(ec.y * cm.y) * ec.y;
    ctx.z = sigm(ec.z * cm.z) * ec.z;
    ctx.w = sigm(ec.w * cm.w) * ec.w;

    float4 P = make_float4(1.f, 1.f, 1.f, 1.f);
    float4 Q = make_float4(0.f, 0.f, 0.f, 0.f);
    float pa = 1.f, qa = 0.f;

    const int t0 = ch * TT;
    const size_t base = ((size_t)b * SS + t0) * DD + d4;
    const float4* Cp = (const float4*)(C + base);
    const float4* Vp = (const float4*)(V + base);
    const float4* Wp = (const float4*)(W + base);
    uint4* DEp = (uint4*)(DE + base);

#pragma unroll 4
    for (int t = 0; t < TT; ++t) {
        const float4 c4 = Cp[t * (DD / 4)];
        const float4 v4 = Vp[t * (DD / 4)];
        const float4 w4 = Wp[t * (DD / 4)];
        float4 dec, e4;
        dec.x = sigm(w4.x * tm.x); dec.y = sigm(w4.y * tm.y);
        dec.z = sigm(w4.z * tm.z); dec.w = sigm(w4.w * tm.w);
        e4.x = __expf(c4.x); e4.y = __expf(c4.y);
        e4.z = __expf(c4.z); e4.w = __expf(c4.w);

        uint4 u;
        u.x = pack_de(dec.x, e4.x); u.y = pack_de(dec.y, e4.y);
        u.z = pack_de(dec.z, e4.z); u.w = pack_de(dec.w, e4.w);
        DEp[t * (DD / 4)] = u;

        Q.x = dec.x * Q.x + (e4.x * v4.x + ctx.x);
        Q.y = dec.y * Q.y + (e4.y * v4.y + ctx.y);
        Q.z = dec.z * Q.z + (e4.z * v4.z + ctx.z);
        Q.w = dec.w * Q.w + (e4.w * v4.w + ctx.w);
        P.x *= dec.x; P.y *= dec.y; P.z *= dec.z; P.w *= dec.w;

        float sd = (dec.x + dec.y) + (dec.z + dec.w);
        float se = (e4.x + e4.y) + (e4.z + e4.w);
        red2(sd, se);
        const float mt = sd * (1.0f / DD);
        pa *= mt;
        qa = mt * qa + se;
        if (lane == 0) {
            mbuf[(size_t)b * SS + t0 + t] = mt;
            ebuf[(size_t)b * SS + t0 + t] = se;
        }
    }

    *(float4*)(Pbuf + (size_t)gc * DD + d4) = P;
    *(float4*)(Qbuf + (size_t)gc * DD + d4) = Q;
    if (lane == 0) { PaBuf[gc] = pa; QaBuf[gc] = qa; }
}

// ---------------------------------------------------------------------------
// Pass 2: two-level scan of chunk transfer functions -> chunk-entry states.
//   128 blocks (b x 8 d-tiles), 256 threads: thread (sub, dl) scans 16 chunk
//   transfers held in registers; LDS combine of the 16 sub-carries; register
//   replay writes bst0. Sequential depth ~48 instead of 256.
//   dt==0 blocks additionally Kogge-Stone the scalar (Pa,Qa) scan -> a0.
// ---------------------------------------------------------------------------
__global__ __launch_bounds__(256) void pass2_kernel(
    const float* __restrict__ Pbuf, const float* __restrict__ Qbuf,
    const float* __restrict__ PaBuf, const float* __restrict__ QaBuf,
    float* __restrict__ bst0, float* __restrict__ a0)
{
    const int b   = blockIdx.x >> 3;
    const int dt  = blockIdx.x & 7;
    const int tid = threadIdx.x;
    const int dl  = tid & (DT - 1);
    const int sub = tid >> 4;
    const int d   = dt * DT + dl;

    __shared__ float cP[SUBS][DT], cQ[SUBS][DT], ent[SUBS][DT];
    __shared__ float sPa[NCH], sQa[NCH];

    // sweep 1: local composite over this thread's 16 chunks (kept in regs)
    const int ch0 = sub * CPS;
    const size_t base = ((size_t)b * NCH + ch0) * DD + d;
    float Pr[CPS], Qr[CPS];
    float p = 1.f, q = 0.f;
#pragma unroll
    for (int i = 0; i < CPS; ++i) {
        Pr[i] = Pbuf[base + (size_t)i * DD];
        Qr[i] = Qbuf[base + (size_t)i * DD];
        q = Pr[i] * q + Qr[i];
        p = Pr[i] * p;
    }
    cP[sub][dl] = p; cQ[sub][dl] = q;
    __syncthreads();

    // combine: entry state per sub-range (init state = 0)
    if (tid < DT) {
        float s = 0.f;
#pragma unroll
        for (int sb = 0; sb < SUBS; ++sb) {
            ent[sb][tid] = s;
            s = cP[sb][tid] * s + cQ[sb][tid];
        }
    }
    __syncthreads();

    // sweep 2: replay from entry state, write bst0
    float s = ent[sub][dl];
#pragma unroll
    for (int i = 0; i < CPS; ++i) {
        bst0[base + (size_t)i * DD] = s;
        s = Pr[i] * s + Qr[i];
    }

    // scalar a-scan (one tile of blocks only; block-uniform branch)
    if (dt == 0) {
        float pa = PaBuf[b * NCH + tid];
        float qa = QaBuf[b * NCH + tid];
#pragma unroll
        for (int off = 1; off < NCH; off <<= 1) {
            sPa[tid] = pa; sQa[tid] = qa;
            __syncthreads();
            if (tid >= off) {
                const float pp = sPa[tid - off], qq = sQa[tid - off];
                qa = pa * qq + qa;
                pa = pa * pp;
            }
            __syncthreads();
        }
        sQa[tid] = qa;
        __syncthreads();
        a0[b * NCH + tid] = (tid == 0) ? 0.f : sQa[tid - 1];
    }
}

// ---------------------------------------------------------------------------
// Pass 3: replay each chunk from its entry state using the bf16 DE side-band
// (no transcendentals except rcp/rsqrt); fuse LayerNorm; write out.
// ---------------------------------------------------------------------------
__global__ __launch_bounds__(NTHR) void pass3_kernel(
    const float* __restrict__ V, const unsigned* __restrict__ DE,
    const float* __restrict__ enc, const float* __restrict__ cmod,
    const float* __restrict__ lnw, const float* __restrict__ lnb,
    const float* __restrict__ bst0, const float* __restrict__ a0,
    const float* __restrict__ mbuf, const float* __restrict__ ebuf,
    float* __restrict__ out)
{
    const int grp  = threadIdx.x >> 5;
    const int lane = threadIdx.x & 31;
    const int gc   = blockIdx.x * GPB + grp;
    const int b    = gc >> 8;
    const int ch   = gc & (NCH - 1);
    const int d4   = lane << 2;

    const float4 cm = *(const float4*)(cmod + d4);
    const float4 ec = *(const float4*)(enc + b * DD + d4);
    float4 ctx;
    ctx.x = sigm(ec.x * cm.x) * ec.x;
    ctx.y = sigm(ec.y * cm.y) * ec.y;
    ctx.z = sigm(ec.z * cm.z) * ec.z;
    ctx.w = sigm(ec.w * cm.w) * ec.w;
    const float4 gw = *(const float4*)(lnw + d4);
    const float4 gb = *(const float4*)(lnb + d4);

    float4 bst = *(const float4*)(bst0 + (size_t)gc * DD + d4);
    float a = a0[gc];

    const int t0 = ch * TT;
    const size_t base = ((size_t)b * SS + t0) * DD + d4;
    const float4* Vp = (const float4*)(V + base);
    const uint4*  DEp = (const uint4*)(DE + base);
    float4* Op = (float4*)(out + base);
    const float* mp = mbuf + (size_t)b * SS + t0;
    const float* ep = ebuf + (size_t)b * SS + t0;

#pragma unroll 4
    for (int t = 0; t < TT; ++t) {
        const float4 v4 = Vp[t * (DD / 4)];
        const uint4  u  = DEp[t * (DD / 4)];
        const float mt = mp[t];
        const float et = ep[t];

        a = mt * a + et;
        bst.x = de_lo(u.x) * bst.x + (de_hi(u.x) * v4.x + ctx.x);
        bst.y = de_lo(u.y) * bst.y + (de_hi(u.y) * v4.y + ctx.y);
        bst.z = de_lo(u.z) * bst.z + (de_hi(u.z) * v4.z + ctx.z);
        bst.w = de_lo(u.w) * bst.w + (de_hi(u.w) * v4.w + ctx.w);

        const float inva = fast_rcp(a + REC_EPS);
        float4 o;
        o.x = bst.x * inva; o.y = bst.y * inva;
        o.z = bst.z * inva; o.w = bst.w * inva;

        float s1 = (o.x + o.y) + (o.z + o.w);
        float s2 = (o.x * o.x + o.y * o.y) + (o.z * o.z + o.w * o.w);
        red2(s1, s2);
        const float mu  = s1 * (1.0f / DD);
        const float var = s2 * (1.0f / DD) - mu * mu;
        const float rs  = rsqrtf(var + LN_EPS);

        float4 r;
        r.x = (o.x - mu) * rs * gw.x + gb.x;
        r.y = (o.y - mu) * rs * gw.y + gb.y;
        r.z = (o.z - mu) * rs * gw.z + gb.z;
        r.w = (o.w - mu) * rs * gw.w + gb.w;
        Op[t * (DD / 4)] = r;
    }
}

extern "C" void kernel_launch(void* const* d_in, const int* in_sizes, int n_in,
                              void* d_out, int out_size, void* d_ws, size_t ws_size,
                              hipStream_t stream)
{
    const float* C    = (const float*)d_in[0];
    const float* V    = (const float*)d_in[1];
    const float* W    = (const float*)d_in[2];
    const float* enc  = (const float*)d_in[3];
    const float* tmod = (const float*)d_in[4];
    const float* cmod = (const float*)d_in[5];
    const float* lnw  = (const float*)d_in[6];
    const float* lnb  = (const float*)d_in[7];
    float* out = (float*)d_out;

    // Workspace layout: DE (32 MB) + scan buffers (~6.6 MB)
    float* ws    = (float*)d_ws;
    unsigned* DEbuf = (unsigned*)ws;                      // BB*SS*DD uints
    float* Pbuf  = ws    + (size_t)BB * SS * DD;          // BB*NCH*DD
    float* Qbuf  = Pbuf  + (size_t)BB * NCH * DD;
    float* bst0  = Qbuf  + (size_t)BB * NCH * DD;
    float* mbuf  = bst0  + (size_t)BB * NCH * DD;         // BB*SS
    float* ebuf  = mbuf  + (size_t)BB * SS;
    float* PaBuf = ebuf  + (size_t)BB * SS;               // BB*NCH
    float* QaBuf = PaBuf + (size_t)BB * NCH;
    float* a0Buf = QaBuf + (size_t)BB * NCH;

    const int nblk = BB * NCH / GPB;   // 1024
    pass1_kernel<<<nblk, NTHR, 0, stream>>>(C, V, W, enc, tmod, cmod, DEbuf,
                                            Pbuf, Qbuf, PaBuf, QaBuf, mbuf, ebuf);
    pass2_kernel<<<BB * 8, 256, 0, stream>>>(Pbuf, Qbuf, PaBuf, QaBuf, bst0, a0Buf);
    pass3_kernel<<<nblk, NTHR, 0, stream>>>(V, DEbuf, enc, cmod, lnw, lnb,
                                            bst0, a0Buf, mbuf, ebuf, out);
}